// Round 8
// baseline (161.272 us; speedup 1.0000x reference)
//
#include <hip/hip_runtime.h>
#include <math.h>

#define D_MODEL 300
#define LSEQ    512
#define NBATCH  300
#define VOCAB   32000
#define SPLIT   16                  // l-chunks for diag
#define LCH     (LSEQ / SPLIT)      // 32 l-values per block
#define NG      4                   // parallel l-streams per block
#define ITER    (LCH / NG)          // 8 l's per lane-stream
#define NR      75                  // 4-elem vec lanes per row (75*4 = 300)
#define KCH     (D_MODEL / 4)       // 75, fc1 k-chunk
#define JPB     4                   // j-rows per fc1 block
#define SCALE   17.32050807568877f  // sqrt(300)

__device__ __forceinline__ unsigned short f2bf(float f) {
    unsigned u = __float_as_uint(f);
    unsigned r = (u + 0x7FFFu + ((u >> 16) & 1u)) >> 16;   // round-nearest-even
    return (unsigned short)r;
}
__device__ __forceinline__ float bf2f(unsigned short v) {
    return __uint_as_float(((unsigned)v) << 16);
}

// emb1 (f32, 9.6M elems) -> bf16 slab. 4 elems per thread.
__global__ void conv_kernel(const float* __restrict__ emb1, unsigned short* __restrict__ e1b) {
    int t = blockIdx.x * blockDim.x + threadIdx.x;
    if (t * 4 >= VOCAB * D_MODEL) return;
    float4 v = ((const float4*)emb1)[t];
    ushort4 o;
    o.x = f2bf(v.x); o.y = f2bf(v.y); o.z = f2bf(v.z); o.w = f2bf(v.w);
    ((ushort4*)e1b)[t] = o;
}

// pe[l, e]: e even -> sin(l * div[e/2]); e odd -> cos(l * div[e/2])
__global__ void pe_kernel(float* __restrict__ pe) {
    int idx = blockIdx.x * blockDim.x + threadIdx.x;
    if (idx >= LSEQ * D_MODEL) return;
    int l = idx / D_MODEL;
    int e = idx - l * D_MODEL;
    int k = e >> 1;
    float dv = expf((float)(2 * k) * (-9.210340371976184f / 300.0f));
    float arg = (float)l * dv;
    pe[idx] = (e & 1) ? cosf(arg) : sinf(arg);
}

// Dm[i][e] += sum_{l in chunk} s[l] * (SCALE*emb1[x1[i,l]][e] + pe[l][e])
// Fully-unrolled gather: all 8 ushort4 row-gathers + 8 float4 pe loads issued
// before any use -> ~2.4 KB in flight per lane (fix for VGPR=20 serialization).
__global__ __launch_bounds__(320) void diag_fused_kernel(
        const int* __restrict__ x1, const int* __restrict__ x2,
        const unsigned short* __restrict__ e1b,
        const float* __restrict__ emb2,
        const float* __restrict__ pe, float* __restrict__ Dm) {
    __shared__ int    x1ch[LCH];
    __shared__ float  sch[LCH];
    __shared__ float4 part[NG][NR];
    const int i   = blockIdx.x;   // batch index (== diagonal index)
    const int sp  = blockIdx.y;   // l-chunk
    const int tid = threadIdx.x;
    const int l0  = sp * LCH;

    if (tid < LCH) {
        const int l = l0 + tid;
        x1ch[tid] = x1[i * LSEQ + l];
        int idx2  = x2[i * LSEQ + l];
        sch[tid]  = emb2[idx2 * D_MODEL + i] * SCALE + pe[l * D_MODEL + i];
    }
    __syncthreads();

    const int g = tid / NR;       // l-stream; handles l = g, g+NG, ...
    const int r = tid - g * NR;   // 4-elem vec index within row

    if (tid < NG * NR) {
        ushort4 ev[ITER];
        float4  pv[ITER];
        #pragma unroll
        for (int t = 0; t < ITER; ++t) {
            const int l = g + t * NG;
            ev[t] = ((const ushort4*)(e1b + (size_t)x1ch[l] * D_MODEL))[r];
            pv[t] = ((const float4*)(pe + (size_t)(l0 + l) * D_MODEL))[r];
        }
        float ax = 0.f, ay = 0.f, az = 0.f, aw = 0.f;
        #pragma unroll
        for (int t = 0; t < ITER; ++t) {
            const float s = sch[g + t * NG];
            ax = fmaf(s, fmaf(bf2f(ev[t].x), SCALE, pv[t].x), ax);
            ay = fmaf(s, fmaf(bf2f(ev[t].y), SCALE, pv[t].y), ay);
            az = fmaf(s, fmaf(bf2f(ev[t].z), SCALE, pv[t].z), az);
            aw = fmaf(s, fmaf(bf2f(ev[t].w), SCALE, pv[t].w), aw);
        }
        part[g][r] = make_float4(ax, ay, az, aw);
    }
    __syncthreads();

    if (g == 0 && tid < NR) {
        float4 p0 = part[0][r], p1 = part[1][r], p2 = part[2][r], p3 = part[3][r];
        float* dst = Dm + i * D_MODEL + 4 * r;
        atomicAdd(dst + 0, p0.x + p1.x + p2.x + p3.x);
        atomicAdd(dst + 1, p0.y + p1.y + p2.y + p3.y);
        atomicAdd(dst + 2, p0.z + p1.z + p2.z + p3.z);
        atomicAdd(dst + 3, p0.w + p1.w + p2.w + p3.w);
    }
}

// fc1 k-split partial, JPB j-rows per block for Dm reuse:
// Hpre[j][e] += sum_{k in chunk} w1[j,k] * Dm[k][e]
__global__ void fc1_kernel(const float* __restrict__ w1, const float* __restrict__ Dm,
                           float* __restrict__ Hpre) {
    const int j0  = blockIdx.x * JPB;
    const int sp  = blockIdx.y;
    const int tid = threadIdx.x;
    const int k0  = sp * KCH;
    if (tid >= D_MODEL) return;
    const float* w1r0 = w1 + (j0 + 0) * D_MODEL + k0;
    const float* w1r1 = w1 + (j0 + 1) * D_MODEL + k0;
    const float* w1r2 = w1 + (j0 + 2) * D_MODEL + k0;
    const float* w1r3 = w1 + (j0 + 3) * D_MODEL + k0;
    float acc0 = 0.0f, acc1 = 0.0f, acc2 = 0.0f, acc3 = 0.0f;
    #pragma unroll 5
    for (int k = 0; k < KCH; ++k) {
        float d = Dm[(k0 + k) * D_MODEL + tid];
        acc0 = fmaf(w1r0[k], d, acc0);
        acc1 = fmaf(w1r1[k], d, acc1);
        acc2 = fmaf(w1r2[k], d, acc2);
        acc3 = fmaf(w1r3[k], d, acc3);
    }
    atomicAdd(&Hpre[(j0 + 0) * D_MODEL + tid], acc0);
    atomicAdd(&Hpre[(j0 + 1) * D_MODEL + tid], acc1);
    atomicAdd(&Hpre[(j0 + 2) * D_MODEL + tid], acc2);
    atomicAdd(&Hpre[(j0 + 3) * D_MODEL + tid], acc3);
}

// Fused bias + relu + fc2 + softmax. Block = 256 thr = 64 e-lanes x 4 j-chunks.
__global__ void fc2_softmax_kernel(const float* __restrict__ Hpre, const float* __restrict__ b1,
                                   const float* __restrict__ w2, const float* __restrict__ b2,
                                   float* __restrict__ out) {
    __shared__ float sm[4][4][64];   // [jc][o][e_loc]
    const int tid   = threadIdx.x;
    const int e_loc = tid & 63;
    const int jc    = tid >> 6;
    const int e     = blockIdx.x * 64 + e_loc;

    float a0 = 0.f, a1 = 0.f, a2 = 0.f, a3 = 0.f;
    if (e < D_MODEL) {
        const int j0 = jc * 75;
        #pragma unroll 5
        for (int j = j0; j < j0 + 75; ++j) {
            float h = fmaxf(Hpre[j * D_MODEL + e] + b1[j], 0.0f);
            a0 = fmaf(h, w2[0 * D_MODEL + j], a0);
            a1 = fmaf(h, w2[1 * D_MODEL + j], a1);
            a2 = fmaf(h, w2[2 * D_MODEL + j], a2);
            a3 = fmaf(h, w2[3 * D_MODEL + j], a3);
        }
    }
    sm[jc][0][e_loc] = a0; sm[jc][1][e_loc] = a1;
    sm[jc][2][e_loc] = a2; sm[jc][3][e_loc] = a3;
    __syncthreads();

    if (jc == 0 && e < D_MODEL) {
        float l0 = b2[0] + sm[0][0][e_loc] + sm[1][0][e_loc] + sm[2][0][e_loc] + sm[3][0][e_loc];
        float l1 = b2[1] + sm[0][1][e_loc] + sm[1][1][e_loc] + sm[2][1][e_loc] + sm[3][1][e_loc];
        float l2 = b2[2] + sm[0][2][e_loc] + sm[1][2][e_loc] + sm[2][2][e_loc] + sm[3][2][e_loc];
        float l3 = b2[3] + sm[0][3][e_loc] + sm[1][3][e_loc] + sm[2][3][e_loc] + sm[3][3][e_loc];
        float m  = fmaxf(fmaxf(l0, l1), fmaxf(l2, l3));
        float x0 = expf(l0 - m), x1 = expf(l1 - m), x2 = expf(l2 - m), x3 = expf(l3 - m);
        float inv = 1.0f / (x0 + x1 + x2 + x3);
        out[e * 4 + 0] = x0 * inv;
        out[e * 4 + 1] = x1 * inv;
        out[e * 4 + 2] = x2 * inv;
        out[e * 4 + 3] = x3 * inv;
    }
}

extern "C" void kernel_launch(void* const* d_in, const int* in_sizes, int n_in,
                              void* d_out, int out_size, void* d_ws, size_t ws_size,
                              hipStream_t stream) {
    const int*   x1   = (const int*)d_in[0];
    const int*   x2   = (const int*)d_in[1];
    const float* emb1 = (const float*)d_in[2];
    const float* emb2 = (const float*)d_in[3];
    const float* w1   = (const float*)d_in[4];
    const float* b1   = (const float*)d_in[5];
    const float* w2   = (const float*)d_in[6];
    const float* b2   = (const float*)d_in[7];
    float* out = (float*)d_out;

    char* ws = (char*)d_ws;
    float*          pe   = (float*)ws;                  // 512*300*4 = 614400 B
    float*          Dm   = (float*)(ws + 614400);       // 300*300*4 = 360000 B
    float*          Hpre = (float*)(ws + 974400);       // 300*300*4 = 360000 B
    unsigned short* e1b  = (unsigned short*)(ws + 1334400);  // 32000*300*2 = 19.2 MB

    // zero the two atomic-accumulated buffers (contiguous)
    (void)hipMemsetAsync(Dm, 0, 2 * 360000, stream);

    conv_kernel<<<(VOCAB * D_MODEL / 4 + 255) / 256, 256, 0, stream>>>(emb1, e1b);
    pe_kernel<<<(LSEQ * D_MODEL + 255) / 256, 256, 0, stream>>>(pe);
    diag_fused_kernel<<<dim3(NBATCH, SPLIT), 320, 0, stream>>>(x1, x2, e1b, emb2, pe, Dm);
    fc1_kernel<<<dim3(D_MODEL / JPB, 4), 320, 0, stream>>>(w1, Dm, Hpre);
    fc2_softmax_kernel<<<(D_MODEL + 63) / 64, 256, 0, stream>>>(Hpre, b1, w2, b2, out);
}

// Round 9
// 160.046 us; speedup vs baseline: 1.0077x; 1.0077x over previous
//
#include <hip/hip_runtime.h>
#include <math.h>

#define D_MODEL 300
#define LSEQ    512
#define NBATCH  300
#define SPLIT   8                   // l-chunks for diag
#define LCH     (LSEQ / SPLIT)      // 64 l-values per block
#define NG      4                   // parallel l-streams per block
#define NR      75                  // float4 lanes per row (75*4 = 300)
#define KCH     (D_MODEL / 4)       // 75, fc1 k-chunk
#define JPB     4                   // j-rows per fc1 block
#define SCALE   17.32050807568877f  // sqrt(300)

// pe[l, e]: e even -> sin(l * div[e/2]); e odd -> cos(l * div[e/2])
__global__ void pe_kernel(float* __restrict__ pe) {
    int idx = blockIdx.x * blockDim.x + threadIdx.x;
    if (idx >= LSEQ * D_MODEL) return;
    int l = idx / D_MODEL;
    int e = idx - l * D_MODEL;
    int k = e >> 1;
    float dv = expf((float)(2 * k) * (-9.210340371976184f / 300.0f));
    float arg = (float)l * dv;
    pe[idx] = (e & 1) ? cosf(arg) : sinf(arg);
}

// Dm[i][e] += sum_{l in chunk} s[l] * (SCALE*emb1[x1[i,l]][e] + pe[l][e])
// Gather order SORTED by vocab index: co-resident blocks sweep the vocab
// table low->high in near-lockstep, so the instantaneous working set
// (~1-2 MB around the current quantile) stays L2-resident -> row reuse
// (~4.8x per row) becomes L2/L3 hits instead of L2-miss fabric traffic.
__global__ void diag_fused_kernel(const int* __restrict__ x1, const int* __restrict__ x2,
                                  const float* __restrict__ emb1, const float* __restrict__ emb2,
                                  const float* __restrict__ pe, float* __restrict__ Dm) {
    __shared__ int    x1ch[LCH];
    __shared__ float  sch[LCH];
    __shared__ int    x1s[LCH];     // sorted by vocab index
    __shared__ float  ss[LCH];      // s-values permuted alongside
    __shared__ int    lperm[LCH];   // original l for each sorted slot
    __shared__ float4 part[NG][NR];
    const int i   = blockIdx.x;   // batch index (== diagonal index)
    const int sp  = blockIdx.y;   // l-chunk
    const int tid = threadIdx.x;
    const int l0  = sp * LCH;

    if (tid < LCH) {
        const int l = l0 + tid;
        x1ch[tid] = x1[i * LSEQ + l];
        int idx2  = x2[i * LSEQ + l];
        sch[tid]  = emb2[idx2 * D_MODEL + i] * SCALE + pe[l * D_MODEL + i];
    }
    __syncthreads();

    // O(LCH^2) rank sort (64 comparisons per thread — trivial)
    if (tid < LCH) {
        const int v = x1ch[tid];
        int rank = 0;
        #pragma unroll 8
        for (int j = 0; j < LCH; ++j) {
            int vj = x1ch[j];
            rank += (vj < v) || (vj == v && j < tid);
        }
        x1s[rank]   = v;
        ss[rank]    = sch[tid];
        lperm[rank] = tid;          // l offset within chunk (for pe row)
    }
    __syncthreads();

    const int g = tid / NR;       // l-stream; handles sorted slots g, g+NG, ...
    const int r = tid - g * NR;   // float4 index within row

    if (tid < NG * NR) {
        float ax = 0.f, ay = 0.f, az = 0.f, aw = 0.f;
        #pragma unroll 4
        for (int l = g; l < LCH; l += NG) {
            const float4 ev = ((const float4*)(emb1 + (size_t)x1s[l] * D_MODEL))[r];
            const float4 pv = ((const float4*)(pe + (size_t)(l0 + lperm[l]) * D_MODEL))[r];
            const float  s  = ss[l];
            ax = fmaf(s, fmaf(ev.x, SCALE, pv.x), ax);
            ay = fmaf(s, fmaf(ev.y, SCALE, pv.y), ay);
            az = fmaf(s, fmaf(ev.z, SCALE, pv.z), az);
            aw = fmaf(s, fmaf(ev.w, SCALE, pv.w), aw);
        }
        part[g][r] = make_float4(ax, ay, az, aw);
    }
    __syncthreads();

    if (g == 0 && tid < NR) {
        float4 p0 = part[0][r], p1 = part[1][r], p2 = part[2][r], p3 = part[3][r];
        float* dst = Dm + i * D_MODEL + 4 * r;
        atomicAdd(dst + 0, p0.x + p1.x + p2.x + p3.x);
        atomicAdd(dst + 1, p0.y + p1.y + p2.y + p3.y);
        atomicAdd(dst + 2, p0.z + p1.z + p2.z + p3.z);
        atomicAdd(dst + 3, p0.w + p1.w + p2.w + p3.w);
    }
}

// fc1 k-split partial, JPB j-rows per block for Dm reuse:
// Hpre[j][e] += sum_{k in chunk} w1[j,k] * Dm[k][e]
__global__ void fc1_kernel(const float* __restrict__ w1, const float* __restrict__ Dm,
                           float* __restrict__ Hpre) {
    const int j0  = blockIdx.x * JPB;
    const int sp  = blockIdx.y;
    const int tid = threadIdx.x;
    const int k0  = sp * KCH;
    if (tid >= D_MODEL) return;
    const float* w1r0 = w1 + (j0 + 0) * D_MODEL + k0;
    const float* w1r1 = w1 + (j0 + 1) * D_MODEL + k0;
    const float* w1r2 = w1 + (j0 + 2) * D_MODEL + k0;
    const float* w1r3 = w1 + (j0 + 3) * D_MODEL + k0;
    float acc0 = 0.0f, acc1 = 0.0f, acc2 = 0.0f, acc3 = 0.0f;
    #pragma unroll 5
    for (int k = 0; k < KCH; ++k) {
        float d = Dm[(k0 + k) * D_MODEL + tid];
        acc0 = fmaf(w1r0[k], d, acc0);
        acc1 = fmaf(w1r1[k], d, acc1);
        acc2 = fmaf(w1r2[k], d, acc2);
        acc3 = fmaf(w1r3[k], d, acc3);
    }
    atomicAdd(&Hpre[(j0 + 0) * D_MODEL + tid], acc0);
    atomicAdd(&Hpre[(j0 + 1) * D_MODEL + tid], acc1);
    atomicAdd(&Hpre[(j0 + 2) * D_MODEL + tid], acc2);
    atomicAdd(&Hpre[(j0 + 3) * D_MODEL + tid], acc3);
}

// Fused bias + relu + fc2 + softmax. Block = 256 thr = 64 e-lanes x 4 j-chunks.
__global__ void fc2_softmax_kernel(const float* __restrict__ Hpre, const float* __restrict__ b1,
                                   const float* __restrict__ w2, const float* __restrict__ b2,
                                   float* __restrict__ out) {
    __shared__ float sm[4][4][64];   // [jc][o][e_loc]
    const int tid   = threadIdx.x;
    const int e_loc = tid & 63;
    const int jc    = tid >> 6;
    const int e     = blockIdx.x * 64 + e_loc;

    float a0 = 0.f, a1 = 0.f, a2 = 0.f, a3 = 0.f;
    if (e < D_MODEL) {
        const int j0 = jc * 75;
        #pragma unroll 5
        for (int j = j0; j < j0 + 75; ++j) {
            float h = fmaxf(Hpre[j * D_MODEL + e] + b1[j], 0.0f);
            a0 = fmaf(h, w2[0 * D_MODEL + j], a0);
            a1 = fmaf(h, w2[1 * D_MODEL + j], a1);
            a2 = fmaf(h, w2[2 * D_MODEL + j], a2);
            a3 = fmaf(h, w2[3 * D_MODEL + j], a3);
        }
    }
    sm[jc][0][e_loc] = a0; sm[jc][1][e_loc] = a1;
    sm[jc][2][e_loc] = a2; sm[jc][3][e_loc] = a3;
    __syncthreads();

    if (jc == 0 && e < D_MODEL) {
        float l0 = b2[0] + sm[0][0][e_loc] + sm[1][0][e_loc] + sm[2][0][e_loc] + sm[3][0][e_loc];
        float l1 = b2[1] + sm[0][1][e_loc] + sm[1][1][e_loc] + sm[2][1][e_loc] + sm[3][1][e_loc];
        float l2 = b2[2] + sm[0][2][e_loc] + sm[1][2][e_loc] + sm[2][2][e_loc] + sm[3][2][e_loc];
        float l3 = b2[3] + sm[0][3][e_loc] + sm[1][3][e_loc] + sm[2][3][e_loc] + sm[3][3][e_loc];
        float m  = fmaxf(fmaxf(l0, l1), fmaxf(l2, l3));
        float x0 = expf(l0 - m), x1 = expf(l1 - m), x2 = expf(l2 - m), x3 = expf(l3 - m);
        float inv = 1.0f / (x0 + x1 + x2 + x3);
        out[e * 4 + 0] = x0 * inv;
        out[e * 4 + 1] = x1 * inv;
        out[e * 4 + 2] = x2 * inv;
        out[e * 4 + 3] = x3 * inv;
    }
}

extern "C" void kernel_launch(void* const* d_in, const int* in_sizes, int n_in,
                              void* d_out, int out_size, void* d_ws, size_t ws_size,
                              hipStream_t stream) {
    const int*   x1   = (const int*)d_in[0];
    const int*   x2   = (const int*)d_in[1];
    const float* emb1 = (const float*)d_in[2];
    const float* emb2 = (const float*)d_in[3];
    const float* w1   = (const float*)d_in[4];
    const float* b1   = (const float*)d_in[5];
    const float* w2   = (const float*)d_in[6];
    const float* b2   = (const float*)d_in[7];
    float* out = (float*)d_out;

    char* ws = (char*)d_ws;
    float* pe   = (float*)ws;                 // 512*300*4 = 614400 B
    float* Dm   = (float*)(ws + 614400);      // 300*300*4 = 360000 B
    float* Hpre = (float*)(ws + 974400);      // 300*300*4 = 360000 B

    // zero the two atomic-accumulated buffers (contiguous)
    (void)hipMemsetAsync(Dm, 0, 2 * 360000, stream);

    pe_kernel<<<(LSEQ * D_MODEL + 255) / 256, 256, 0, stream>>>(pe);
    diag_fused_kernel<<<dim3(NBATCH, SPLIT), 320, 0, stream>>>(x1, x2, emb1, emb2, pe, Dm);
    fc1_kernel<<<dim3(D_MODEL / JPB, 4), 320, 0, stream>>>(w1, Dm, Hpre);
    fc2_softmax_kernel<<<(D_MODEL + 63) / 64, 256, 0, stream>>>(Hpre, b1, w2, b2, out);
}

// Round 10
// 159.072 us; speedup vs baseline: 1.0138x; 1.0061x over previous
//
#include <hip/hip_runtime.h>
#include <math.h>

#define D_MODEL 300
#define LSEQ    512
#define NBATCH  300
#define NBUK    8                   // vocab octiles (one per XCD)
#define BCAP    160                 // bucket capacity (mean 64, sd 7.4 -> safe)
#define NG      4                   // parallel entry-streams per gather block
#define NR      75                  // float4 lanes per row (75*4 = 300)
#define KCH     (D_MODEL / 4)       // 75, fc1 k-chunk
#define JPB     4                   // j-rows per fc1 block
#define SCALE   17.32050807568877f  // sqrt(300)

// pe[l, e]: e even -> sin(l * div[e/2]); e odd -> cos(l * div[e/2])
__global__ void pe_kernel(float* __restrict__ pe) {
    int idx = blockIdx.x * blockDim.x + threadIdx.x;
    if (idx >= LSEQ * D_MODEL) return;
    int l = idx / D_MODEL;
    int e = idx - l * D_MODEL;
    int k = e >> 1;
    float dv = expf((float)(2 * k) * (-9.210340371976184f / 300.0f));
    float arg = (float)l * dv;
    pe[idx] = (e & 1) ? cosf(arg) : sinf(arg);
}

// Per sequence i: compute s[l] = emb2[x2[i,l], i]*SCALE + pe[l,i], then bucket
// (v = x1[i,l], l, s) by vocab octile v>>12. Key packs (l<<15)|v (v<32768, l<512).
__global__ void bucket_kernel(const int* __restrict__ x1, const int* __restrict__ x2,
                              const float* __restrict__ emb2, const float* __restrict__ pe,
                              int* __restrict__ keybuf, float* __restrict__ valbuf,
                              int* __restrict__ cntg) {
    __shared__ int cnt[NBUK];
    const int i = blockIdx.x;
    const int l = threadIdx.x;
    if (l < NBUK) cnt[l] = 0;
    __syncthreads();
    const int v    = x1[i * LSEQ + l];
    const int idx2 = x2[i * LSEQ + l];
    const float s  = emb2[idx2 * D_MODEL + i] * SCALE + pe[l * D_MODEL + i];
    const int b    = v >> 12;
    const int pos  = atomicAdd(&cnt[b], 1);
    const int off  = (i * NBUK + b) * BCAP + pos;
    keybuf[off] = (l << 15) | v;
    valbuf[off] = s;
    __syncthreads();
    if (l < NBUK) cntg[i * NBUK + l] = cnt[l];
}

// Gather: block (octile b, seq i) reads ONLY vocab slice b (<=4.9 MB).
// blockIdx.x is the fast dim -> round-robin XCD dispatch pins slice b to XCD b,
// so the slice stays L2-resident across all 300 i-blocks touching it.
// Dm[i][e] += sum_entries s * (SCALE*emb1[v][e] + pe[l][e])
__global__ void diag_gather_kernel(const int* __restrict__ keybuf, const float* __restrict__ valbuf,
                                   const int* __restrict__ cntg,
                                   const float* __restrict__ emb1, const float* __restrict__ pe,
                                   float* __restrict__ Dm) {
    __shared__ int    key[BCAP];
    __shared__ float  val[BCAP];
    __shared__ float4 part[NG][NR];
    const int b   = blockIdx.x;   // octile (-> XCD, by round-robin assumption)
    const int i   = blockIdx.y;   // sequence / diagonal index
    const int tid = threadIdx.x;
    const int base = (i * NBUK + b) * BCAP;
    const int n   = cntg[i * NBUK + b];

    for (int t = tid; t < n; t += blockDim.x) {
        key[t] = keybuf[base + t];
        val[t] = valbuf[base + t];
    }
    __syncthreads();

    const int g = tid / NR;       // entry-stream
    const int r = tid - g * NR;   // float4 index within row

    if (tid < NG * NR) {
        float ax = 0.f, ay = 0.f, az = 0.f, aw = 0.f;
        for (int t = g; t < n; t += NG) {
            const int   k = key[t];
            const int   v = k & 0x7FFF;
            const int   l = k >> 15;
            const float4 ev = ((const float4*)(emb1 + (size_t)v * D_MODEL))[r];
            const float4 pv = ((const float4*)(pe + (size_t)l * D_MODEL))[r];
            const float  s  = val[t];
            ax = fmaf(s, fmaf(ev.x, SCALE, pv.x), ax);
            ay = fmaf(s, fmaf(ev.y, SCALE, pv.y), ay);
            az = fmaf(s, fmaf(ev.z, SCALE, pv.z), az);
            aw = fmaf(s, fmaf(ev.w, SCALE, pv.w), aw);
        }
        part[g][r] = make_float4(ax, ay, az, aw);
    }
    __syncthreads();

    if (g == 0 && tid < NR) {
        float4 p0 = part[0][r], p1 = part[1][r], p2 = part[2][r], p3 = part[3][r];
        float* dst = Dm + i * D_MODEL + 4 * r;
        atomicAdd(dst + 0, p0.x + p1.x + p2.x + p3.x);
        atomicAdd(dst + 1, p0.y + p1.y + p2.y + p3.y);
        atomicAdd(dst + 2, p0.z + p1.z + p2.z + p3.z);
        atomicAdd(dst + 3, p0.w + p1.w + p2.w + p3.w);
    }
}

// fc1 k-split partial, JPB j-rows per block for Dm reuse:
// Hpre[j][e] += sum_{k in chunk} w1[j,k] * Dm[k][e]
__global__ void fc1_kernel(const float* __restrict__ w1, const float* __restrict__ Dm,
                           float* __restrict__ Hpre) {
    const int j0  = blockIdx.x * JPB;
    const int sp  = blockIdx.y;
    const int tid = threadIdx.x;
    const int k0  = sp * KCH;
    if (tid >= D_MODEL) return;
    const float* w1r0 = w1 + (j0 + 0) * D_MODEL + k0;
    const float* w1r1 = w1 + (j0 + 1) * D_MODEL + k0;
    const float* w1r2 = w1 + (j0 + 2) * D_MODEL + k0;
    const float* w1r3 = w1 + (j0 + 3) * D_MODEL + k0;
    float acc0 = 0.0f, acc1 = 0.0f, acc2 = 0.0f, acc3 = 0.0f;
    #pragma unroll 5
    for (int k = 0; k < KCH; ++k) {
        float d = Dm[(k0 + k) * D_MODEL + tid];
        acc0 = fmaf(w1r0[k], d, acc0);
        acc1 = fmaf(w1r1[k], d, acc1);
        acc2 = fmaf(w1r2[k], d, acc2);
        acc3 = fmaf(w1r3[k], d, acc3);
    }
    atomicAdd(&Hpre[(j0 + 0) * D_MODEL + tid], acc0);
    atomicAdd(&Hpre[(j0 + 1) * D_MODEL + tid], acc1);
    atomicAdd(&Hpre[(j0 + 2) * D_MODEL + tid], acc2);
    atomicAdd(&Hpre[(j0 + 3) * D_MODEL + tid], acc3);
}

// Fused bias + relu + fc2 + softmax. Block = 256 thr = 64 e-lanes x 4 j-chunks.
__global__ void fc2_softmax_kernel(const float* __restrict__ Hpre, const float* __restrict__ b1,
                                   const float* __restrict__ w2, const float* __restrict__ b2,
                                   float* __restrict__ out) {
    __shared__ float sm[4][4][64];   // [jc][o][e_loc]
    const int tid   = threadIdx.x;
    const int e_loc = tid & 63;
    const int jc    = tid >> 6;
    const int e     = blockIdx.x * 64 + e_loc;

    float a0 = 0.f, a1 = 0.f, a2 = 0.f, a3 = 0.f;
    if (e < D_MODEL) {
        const int j0 = jc * 75;
        #pragma unroll 5
        for (int j = j0; j < j0 + 75; ++j) {
            float h = fmaxf(Hpre[j * D_MODEL + e] + b1[j], 0.0f);
            a0 = fmaf(h, w2[0 * D_MODEL + j], a0);
            a1 = fmaf(h, w2[1 * D_MODEL + j], a1);
            a2 = fmaf(h, w2[2 * D_MODEL + j], a2);
            a3 = fmaf(h, w2[3 * D_MODEL + j], a3);
        }
    }
    sm[jc][0][e_loc] = a0; sm[jc][1][e_loc] = a1;
    sm[jc][2][e_loc] = a2; sm[jc][3][e_loc] = a3;
    __syncthreads();

    if (jc == 0 && e < D_MODEL) {
        float l0 = b2[0] + sm[0][0][e_loc] + sm[1][0][e_loc] + sm[2][0][e_loc] + sm[3][0][e_loc];
        float l1 = b2[1] + sm[0][1][e_loc] + sm[1][1][e_loc] + sm[2][1][e_loc] + sm[3][1][e_loc];
        float l2 = b2[2] + sm[0][2][e_loc] + sm[1][2][e_loc] + sm[2][2][e_loc] + sm[3][2][e_loc];
        float l3 = b2[3] + sm[0][3][e_loc] + sm[1][3][e_loc] + sm[2][3][e_loc] + sm[3][3][e_loc];
        float m  = fmaxf(fmaxf(l0, l1), fmaxf(l2, l3));
        float x0 = expf(l0 - m), x1 = expf(l1 - m), x2 = expf(l2 - m), x3 = expf(l3 - m);
        float inv = 1.0f / (x0 + x1 + x2 + x3);
        out[e * 4 + 0] = x0 * inv;
        out[e * 4 + 1] = x1 * inv;
        out[e * 4 + 2] = x2 * inv;
        out[e * 4 + 3] = x3 * inv;
    }
}

extern "C" void kernel_launch(void* const* d_in, const int* in_sizes, int n_in,
                              void* d_out, int out_size, void* d_ws, size_t ws_size,
                              hipStream_t stream) {
    const int*   x1   = (const int*)d_in[0];
    const int*   x2   = (const int*)d_in[1];
    const float* emb1 = (const float*)d_in[2];
    const float* emb2 = (const float*)d_in[3];
    const float* w1   = (const float*)d_in[4];
    const float* b1   = (const float*)d_in[5];
    const float* w2   = (const float*)d_in[6];
    const float* b2   = (const float*)d_in[7];
    float* out = (float*)d_out;

    char* ws = (char*)d_ws;
    float* pe     = (float*)ws;                   // 614400 B
    float* Dm     = (float*)(ws + 614400);        // 360000 B
    float* Hpre   = (float*)(ws + 974400);        // 360000 B
    int*   keybuf = (int*)(ws + 1334400);         // 300*8*160*4 = 1536000 B
    float* valbuf = (float*)(ws + 2870400);       // 1536000 B
    int*   cntg   = (int*)(ws + 4406400);         // 9600 B

    // zero the two atomic-accumulated buffers (contiguous)
    (void)hipMemsetAsync(Dm, 0, 2 * 360000, stream);

    pe_kernel<<<(LSEQ * D_MODEL + 255) / 256, 256, 0, stream>>>(pe);
    bucket_kernel<<<NBATCH, LSEQ, 0, stream>>>(x1, x2, emb2, pe, keybuf, valbuf, cntg);
    diag_gather_kernel<<<dim3(NBUK, NBATCH), 320, 0, stream>>>(keybuf, valbuf, cntg, emb1, pe, Dm);
    fc1_kernel<<<dim3(D_MODEL / JPB, 4), 320, 0, stream>>>(w1, Dm, Hpre);
    fc2_softmax_kernel<<<(D_MODEL + 63) / 64, 256, 0, stream>>>(Hpre, b1, w2, b2, out);
}